// Round 1
// baseline (410.184 us; speedup 1.0000x reference)
//
#include <hip/hip_runtime.h>
#include <cmath>

#define D_ 4096
#define H_ 32
#define HD_ 128
#define B_ 8
#define MAXSEQ_ 2048
#define AL_ 10
#define FF_ 11008
#define SCALE_ 0.08838834764831845f   // 1/sqrt(128)
#define EPS_ 1e-5f

// ---------------- rmsnorm: one block per row (8 rows, D=4096) ----------------
__global__ __launch_bounds__(256) void rmsnorm_k(const float* __restrict__ in,
                                                 const float* __restrict__ w,
                                                 float* __restrict__ out) {
  int b = blockIdx.x, tid = threadIdx.x;
  const float* x = in + (size_t)b * D_;
  float ss = 0.f;
  for (int i = tid; i < D_; i += 256) { float v = x[i]; ss += v * v; }
  __shared__ float red[256];
  red[tid] = ss; __syncthreads();
  for (int s = 128; s; s >>= 1) { if (tid < s) red[tid] += red[tid + s]; __syncthreads(); }
  float r = rsqrtf(red[0] / (float)D_ + EPS_);
  float* o = out + (size_t)b * D_;
  for (int i = tid; i < D_; i += 256) o[i] = x[i] * r * w[i];
}

__global__ void copy_k(const float* __restrict__ in, float* __restrict__ out, int n) {
  int i = blockIdx.x * 256 + threadIdx.x;
  if (i < n) out[i] = in[i];
}

// ---------------- generic split-K GEMV with atomic accumulation ----------------
// X: ROWS x K row-major.  W (per z): K x N row-major.  Y += X @ W.
// grid = (ceil((N/2)/256), K/CHUNK, nmat); block = 256.
template<int ROWS, int CHUNK>
__global__ __launch_bounds__(256) void gemv_atomic(
    const float* __restrict__ X,
    const float* __restrict__ Wa, const float* __restrict__ Wb, const float* __restrict__ Wc,
    float* __restrict__ Ya, float* __restrict__ Yb, float* __restrict__ Yc,
    int N, int K) {
  constexpr int RS = (ROWS + 3) & ~3;            // pad rows to float4 multiple
  const float* W = (blockIdx.z == 0) ? Wa : (blockIdx.z == 1) ? Wb : Wc;
  float*       Y = (blockIdx.z == 0) ? Ya : (blockIdx.z == 1) ? Yb : Yc;
  __shared__ float xs[CHUNK][RS];
  int tid = threadIdx.x;
  int i0 = blockIdx.y * CHUNK;
  for (int idx = tid; idx < ROWS * CHUNK; idx += 256) {
    int r = idx / CHUNK, ii = idx - r * CHUNK;
    xs[ii][r] = X[(size_t)r * K + i0 + ii];
  }
  __syncthreads();
  int N2 = N >> 1;
  int j2 = blockIdx.x * 256 + tid;               // float2 column index
  if (j2 >= N2) return;
  float2 acc[ROWS];
#pragma unroll
  for (int r = 0; r < ROWS; ++r) acc[r] = make_float2(0.f, 0.f);
  const float2* W2 = (const float2*)W;
  for (int ii = 0; ii < CHUNK; ++ii) {
    float2 w = W2[(size_t)(i0 + ii) * N2 + j2];
    float xr[RS];
#pragma unroll
    for (int q = 0; q < RS / 4; ++q)
      *(float4*)&xr[4 * q] = *(const float4*)&xs[ii][4 * q];
#pragma unroll
    for (int r = 0; r < ROWS; ++r) { acc[r].x += xr[r] * w.x; acc[r].y += xr[r] * w.y; }
  }
#pragma unroll
  for (int r = 0; r < ROWS; ++r) {
    atomicAdd(&Y[(size_t)r * N + 2 * j2],     acc[r].x);
    atomicAdd(&Y[(size_t)r * N + 2 * j2 + 1], acc[r].y);
  }
}

// ---------------- RoPE in-place on q (rows 0..7) and new k (rows 0..7) ----------------
__global__ void rope_k(float* __restrict__ qp, float* __restrict__ kp,
                       const float* __restrict__ fc, const float* __restrict__ fs) {
  int tid = blockIdx.x * 256 + threadIdx.x;      // 32768 = 2 tensors * 8b * 2048 pairs
  if (tid >= 32768) return;
  float* buf = (tid & 16384) ? kp : qp;
  int p = tid & 16383;
  int b = p >> 11;
  int rem = p & 2047;
  int h = rem >> 6, i = rem & 63;
  size_t base = (size_t)b * D_ + h * HD_ + 2 * i;
  float a = buf[base], bb = buf[base + 1];
  float c = fc[i], s = fs[i];
  buf[base]     = a * c - bb * s;
  buf[base + 1] = a * s + bb * c;
}

// ---------------- attention pass 1: per (b,h,chunk-of-256) partial ----------------
__global__ __launch_bounds__(256) void attn_partial(
    const float* __restrict__ qp,   // 18 x 4096 (rows 0..7 = q, post-rope)
    const float* __restrict__ kp,   // rows 0..7 = new k (post-rope)
    const float* __restrict__ vp,   // rows 0..7 = new v
    const float* __restrict__ ck,   // cache_k (B, 2048, H, HD)
    const float* __restrict__ cv,   // cache_v
    float* __restrict__ part) {     // 2048 x 132: [m, l, pad, pad, o[128]]
  int idx = blockIdx.x;
  int c = idx & 7, bh = idx >> 3;
  int h = bh & 31, b = bh >> 5;
  int tid = threadIdx.x, wave = tid >> 6, lane = tid & 63;
  __shared__ float sc[256];
  __shared__ float red[256];
  __shared__ float ob[4][128];
  int t0 = c * 256;
  float2 qv = *(const float2*)&qp[(size_t)b * D_ + h * HD_ + 2 * lane];
  // scores
  for (int k = 0; k < 64; ++k) {
    int tl = wave * 64 + k;
    int t = t0 + tl;
    const float* kptr = (t == MAXSEQ_ - 1)
        ? &kp[(size_t)b * D_ + h * HD_]
        : &ck[(((size_t)b * MAXSEQ_ + t) * H_ + h) * HD_];
    float2 kv = *(const float2*)&kptr[2 * lane];
    float s = qv.x * kv.x + qv.y * kv.y;
    for (int off = 32; off; off >>= 1) s += __shfl_xor(s, off);
    if (lane == 0) sc[tl] = s * SCALE_;
  }
  __syncthreads();
  // softmax over the 256 chunk scores (partial: m, l)
  float sv = sc[tid];
  red[tid] = sv; __syncthreads();
  for (int s = 128; s; s >>= 1) { if (tid < s) red[tid] = fmaxf(red[tid], red[tid + s]); __syncthreads(); }
  float m = red[0]; __syncthreads();
  float p = __expf(sv - m);
  sc[tid] = p;
  red[tid] = p; __syncthreads();
  for (int s = 128; s; s >>= 1) { if (tid < s) red[tid] += red[tid + s]; __syncthreads(); }
  float l = red[0];
  // o = sum p_t * v_t ; one t per wave, float2 per lane
  float2 acc = make_float2(0.f, 0.f);
  for (int tl = wave; tl < 256; tl += 4) {
    int t = t0 + tl;
    const float* vptr = (t == MAXSEQ_ - 1)
        ? &vp[(size_t)b * D_ + h * HD_]
        : &cv[(((size_t)b * MAXSEQ_ + t) * H_ + h) * HD_];
    float2 vv = *(const float2*)&vptr[2 * lane];
    float pp = sc[tl];
    acc.x += pp * vv.x; acc.y += pp * vv.y;
  }
  ob[wave][2 * lane] = acc.x;
  ob[wave][2 * lane + 1] = acc.y;
  __syncthreads();
  float* po = &part[(size_t)idx * 132];
  if (tid == 0) { po[0] = m; po[1] = l; }
  if (tid < 128) po[4 + tid] = ob[0][tid] + ob[1][tid] + ob[2][tid] + ob[3][tid];
}

// ---------------- attention pass 2: combine chunks + adapter attention + gate ----------------
__global__ __launch_bounds__(128) void attn_combine(
    const float* __restrict__ part,
    const float* __restrict__ qp,
    const float* __restrict__ kvk,  // rows 8..17 = ak
    const float* __restrict__ kvv,  // rows 8..17 = av
    const float* __restrict__ gate,
    float* __restrict__ attn) {
  int bh = blockIdx.x;
  int h = bh & 31, b = bh >> 5;
  int tid = threadIdx.x;            // = d in [0,128)
  const float* pb = &part[(size_t)bh * 8 * 132];
  float mc[8], lc[8];
  float M = -INFINITY;
  for (int c = 0; c < 8; ++c) { mc[c] = pb[c * 132]; lc[c] = pb[c * 132 + 1]; M = fmaxf(M, mc[c]); }
  float L = 0.f, O = 0.f;
  for (int c = 0; c < 8; ++c) {
    float e = __expf(mc[c] - M);
    L += e * lc[c];
    O += e * pb[c * 132 + 4 + tid];
  }
  float main_out = O / L;
  // adapter attention (10 keys, no rope, raw adapter proj)
  float qd = qp[(size_t)b * D_ + h * HD_ + tid];
  __shared__ float red[128];
  __shared__ float sa[10];
  for (int j = 0; j < 10; ++j) {
    float prod = qd * kvk[(size_t)(8 + j) * D_ + h * HD_ + tid];
    red[tid] = prod; __syncthreads();
    for (int s = 64; s; s >>= 1) { if (tid < s) red[tid] += red[tid + s]; __syncthreads(); }
    if (tid == 0) sa[j] = red[0] * SCALE_;
    __syncthreads();
  }
  float ma = -INFINITY;
  for (int j = 0; j < 10; ++j) ma = fmaxf(ma, sa[j]);
  float la = 0.f, pj[10];
  for (int j = 0; j < 10; ++j) { pj[j] = __expf(sa[j] - ma); la += pj[j]; }
  float ao = 0.f;
  for (int j = 0; j < 10; ++j) ao += pj[j] * kvv[(size_t)(8 + j) * D_ + h * HD_ + tid];
  ao /= la;
  float g = tanhf(gate[h]);
  attn[(size_t)b * D_ + h * HD_ + tid] = main_out + g * ao;
}

__global__ void silu_mul_k(const float* __restrict__ g1, const float* __restrict__ g3,
                           float* __restrict__ g, int n) {
  int i = blockIdx.x * 256 + threadIdx.x;
  if (i < n) { float a = g1[i]; g[i] = (a / (1.f + __expf(-a))) * g3[i]; }
}

extern "C" void kernel_launch(void* const* d_in, const int* in_sizes, int n_in,
                              void* d_out, int out_size, void* d_ws, size_t ws_size,
                              hipStream_t stream) {
  (void)in_sizes; (void)n_in; (void)out_size; (void)ws_size;
  const float* x       = (const float*)d_in[0];
  const float* adapter = (const float*)d_in[1];
  const float* ck      = (const float*)d_in[2];
  const float* cv      = (const float*)d_in[3];
  const float* fc      = (const float*)d_in[4];
  const float* fs      = (const float*)d_in[5];
  const float* wq      = (const float*)d_in[6];
  const float* wk      = (const float*)d_in[7];
  const float* wv      = (const float*)d_in[8];
  const float* wo      = (const float*)d_in[9];
  const float* gate    = (const float*)d_in[10];
  const float* anw     = (const float*)d_in[11];
  const float* fnw     = (const float*)d_in[12];
  const float* w1      = (const float*)d_in[13];
  const float* w2      = (const float*)d_in[14];
  const float* w3      = (const float*)d_in[15];
  float* out = (float*)d_out;

  float* ws   = (float*)d_ws;
  float* xa   = ws;                    // 18*4096 (rows 0..7 = rmsnorm(x), 8..17 = adapter)
  float* qp   = xa + 18 * D_;          // 18*4096 (rows 0..7 used)
  float* kp   = qp + 18 * D_;          // 18*4096 (rows 0..7 = new k, 8..17 = ak)
  float* vp   = kp + 18 * D_;          // 18*4096 (rows 0..7 = new v, 8..17 = av)
  float* part = vp + 18 * D_;          // 2048*132
  float* attn = part + 2048 * 132;     // 8*4096
  float* hbuf = attn + 8 * D_;         // 8*4096
  float* hn   = hbuf + 8 * D_;         // 8*4096
  float* g1   = hn + 8 * D_;           // 8*11008
  float* g3b  = g1 + 8 * FF_;          // 8*11008
  float* gb   = g3b + 8 * FF_;         // 8*11008

  // 1) xn = rmsnorm(x); xa rows 8..17 = adapter
  rmsnorm_k<<<8, 256, 0, stream>>>(x, anw, xa);
  copy_k<<<(AL_ * D_ + 255) / 256, 256, 0, stream>>>(adapter, xa + 8 * D_, AL_ * D_);
  // 2) QKV (+adapter K/V) projections
  hipMemsetAsync(qp, 0, (size_t)3 * 18 * D_ * sizeof(float), stream);
  gemv_atomic<18, 256><<<dim3(8, 16, 3), 256, 0, stream>>>(xa, wq, wk, wv, qp, kp, vp, D_, D_);
  // 3) RoPE on q rows 0..7 and new-k rows 0..7
  rope_k<<<128, 256, 0, stream>>>(qp, kp, fc, fs);
  // 4) flash-decode attention over 2048 positions (pos 2047 = new k/v)
  attn_partial<<<2048, 256, 0, stream>>>(qp, kp, vp, ck, cv, part);
  attn_combine<<<256, 128, 0, stream>>>(part, qp, kp, vp, gate, attn);
  // 5) h = x + attn @ wo
  copy_k<<<128, 256, 0, stream>>>(x, hbuf, 8 * D_);
  gemv_atomic<8, 128><<<dim3(8, 32, 1), 256, 0, stream>>>(attn, wo, wo, wo, hbuf, hbuf, hbuf, D_, D_);
  // 6) hn = rmsnorm(h); FFN
  rmsnorm_k<<<8, 256, 0, stream>>>(hbuf, fnw, hn);
  hipMemsetAsync(g1, 0, (size_t)2 * 8 * FF_ * sizeof(float), stream);
  gemv_atomic<8, 256><<<dim3(22, 16, 2), 256, 0, stream>>>(hn, w1, w3, w3, g1, g3b, g3b, FF_, D_);
  silu_mul_k<<<(8 * FF_ + 255) / 256, 256, 0, stream>>>(g1, g3b, gb, 8 * FF_);
  // 7) out = h + (silu(h@w1)*(h@w3)) @ w2
  copy_k<<<128, 256, 0, stream>>>(hbuf, out, 8 * D_);
  gemv_atomic<8, 256><<<dim3(8, 43, 1), 256, 0, stream>>>(gb, w2, w2, w2, out, out, out, D_, FF_);
}